// Round 1
// baseline (21.574 us; speedup 1.0000x reference)
//
#include <hip/hip_runtime.h>
#include <math.h>

#define M_CP   256
#define N_PTS  32768
#define BATCH  4

__global__ __launch_bounds__(256) void rbf_tps_kernel(
    const float* __restrict__ sparse_disp,   // (B, M, 3)
    const float* __restrict__ original_cp,   // (B, M, 3)
    const float* __restrict__ original_dense,// (B, N, 3)
    float* __restrict__ out)                 // (B, N, 3)
{
    __shared__ float cx[M_CP], cy[M_CP], cz[M_CP];
    __shared__ float sx[M_CP], sy[M_CP], sz[M_CP];

    const int blocks_per_b = N_PTS / 256;            // 128
    const int b     = blockIdx.x / blocks_per_b;
    const int nbase = (blockIdx.x % blocks_per_b) * 256;
    const int t     = threadIdx.x;

    // Stage control points and pre-scaled sparse displacements into LDS.
    // K_ref = r^2 * ln(r + 1e-6) ~= r^2 * 0.5*ln(2) * log2(r^2)
    // Fold c = 0.5*ln(2) into the staged sparse_disp.
    {
        const float* cpb = original_cp + (size_t)b * M_CP * 3;
        const float* sdb = sparse_disp + (size_t)b * M_CP * 3;
        const float c = 0.34657359027997264f;  // 0.5 * ln(2)
        cx[t] = cpb[t * 3 + 0];
        cy[t] = cpb[t * 3 + 1];
        cz[t] = cpb[t * 3 + 2];
        sx[t] = sdb[t * 3 + 0] * c;
        sy[t] = sdb[t * 3 + 1] * c;
        sz[t] = sdb[t * 3 + 2] * c;
    }
    __syncthreads();

    const int n = nbase + t;
    const float* dp = original_dense + ((size_t)b * N_PTS + n) * 3;
    const float px = dp[0], py = dp[1], pz = dp[2];

    float ax = 0.f, ay = 0.f, az = 0.f;

    #pragma unroll 8
    for (int m = 0; m < M_CP; ++m) {
        float dx = px - cx[m];
        float dy = py - cy[m];
        float dz = pz - cz[m];
        float r2 = fmaf(dx, dx, fmaf(dy, dy, dz * dz));
        float l  = __log2f(r2);            // v_log_f32
        float K  = (r2 > 0.f) ? r2 * l : 0.f;  // guard 0 * -inf
        ax = fmaf(K, sx[m], ax);
        ay = fmaf(K, sy[m], ay);
        az = fmaf(K, sz[m], az);
    }

    float* op = out + ((size_t)b * N_PTS + n) * 3;
    op[0] = ax; op[1] = ay; op[2] = az;
}

extern "C" void kernel_launch(void* const* d_in, const int* in_sizes, int n_in,
                              void* d_out, int out_size, void* d_ws, size_t ws_size,
                              hipStream_t stream) {
    const float* sparse_disp    = (const float*)d_in[0];
    const float* original_cp    = (const float*)d_in[1];
    const float* original_dense = (const float*)d_in[2];
    float* out = (float*)d_out;

    dim3 grid(BATCH * (N_PTS / 256));  // 512 blocks
    dim3 block(256);
    rbf_tps_kernel<<<grid, block, 0, stream>>>(sparse_disp, original_cp,
                                               original_dense, out);
}

// Round 2
// 20.510 us; speedup vs baseline: 1.0519x; 1.0519x over previous
//
#include <hip/hip_runtime.h>
#include <math.h>

#define M_CP   256
#define N_PTS  32768
#define BATCH  4

__global__ __launch_bounds__(256) void rbf_tps_kernel(
    const float* __restrict__ sparse_disp,   // (B, M, 3)
    const float* __restrict__ original_cp,   // (B, M, 3)
    const float* __restrict__ original_dense,// (B, N, 3)
    float* __restrict__ out)                 // (B, N, 3)
{
    __shared__ float cx[M_CP], cy[M_CP], cz[M_CP];
    __shared__ float sx[M_CP], sy[M_CP], sz[M_CP];

    // 256 blocks: 64 per batch, each handles 512 points (2 per thread).
    const int blocks_per_b = 64;
    const int b     = blockIdx.x / blocks_per_b;
    const int nbase = (blockIdx.x % blocks_per_b) * 512;
    const int t     = threadIdx.x;

    // Stage control points and pre-scaled sparse displacements into LDS.
    // K_ref = r^2 * ln(r + 1e-6) ~= r^2 * 0.5*ln(2) * log2(r^2)
    {
        const float* cpb = original_cp + (size_t)b * M_CP * 3;
        const float* sdb = sparse_disp + (size_t)b * M_CP * 3;
        const float c = 0.34657359027997264f;  // 0.5 * ln(2)
        cx[t] = cpb[t * 3 + 0];
        cy[t] = cpb[t * 3 + 1];
        cz[t] = cpb[t * 3 + 2];
        sx[t] = sdb[t * 3 + 0] * c;
        sy[t] = sdb[t * 3 + 1] * c;
        sz[t] = sdb[t * 3 + 2] * c;
    }
    __syncthreads();

    const int n0 = nbase + t;         // point 0
    const int n1 = nbase + 256 + t;   // point 1 (stride 256 => coalesced)

    const float* dp0 = original_dense + ((size_t)b * N_PTS + n0) * 3;
    const float* dp1 = original_dense + ((size_t)b * N_PTS + n1) * 3;
    const float px0 = dp0[0], py0 = dp0[1], pz0 = dp0[2];
    const float px1 = dp1[0], py1 = dp1[1], pz1 = dp1[2];

    float ax0 = 0.f, ay0 = 0.f, az0 = 0.f;
    float ax1 = 0.f, ay1 = 0.f, az1 = 0.f;

    for (int m0 = 0; m0 < M_CP; m0 += 4) {
        // One ds_read_b128 per array per 4 control points.
        float4 vcx = *(const float4*)&cx[m0];
        float4 vcy = *(const float4*)&cy[m0];
        float4 vcz = *(const float4*)&cz[m0];
        float4 vsx = *(const float4*)&sx[m0];
        float4 vsy = *(const float4*)&sy[m0];
        float4 vsz = *(const float4*)&sz[m0];

        const float cxa[4] = {vcx.x, vcx.y, vcx.z, vcx.w};
        const float cya[4] = {vcy.x, vcy.y, vcy.z, vcy.w};
        const float cza[4] = {vcz.x, vcz.y, vcz.z, vcz.w};
        const float sxa[4] = {vsx.x, vsx.y, vsx.z, vsx.w};
        const float sya[4] = {vsy.x, vsy.y, vsy.z, vsy.w};
        const float sza[4] = {vsz.x, vsz.y, vsz.z, vsz.w};

        #pragma unroll
        for (int k = 0; k < 4; ++k) {
            // point 0
            float dx0 = px0 - cxa[k];
            float dy0 = py0 - cya[k];
            float dz0 = pz0 - cza[k];
            float r20 = fmaf(dx0, dx0, fmaf(dy0, dy0, dz0 * dz0));
            float K0  = r20 * __log2f(fmaxf(r20, 1e-30f));
            ax0 = fmaf(K0, sxa[k], ax0);
            ay0 = fmaf(K0, sya[k], ay0);
            az0 = fmaf(K0, sza[k], az0);
            // point 1
            float dx1 = px1 - cxa[k];
            float dy1 = py1 - cya[k];
            float dz1 = pz1 - cza[k];
            float r21 = fmaf(dx1, dx1, fmaf(dy1, dy1, dz1 * dz1));
            float K1  = r21 * __log2f(fmaxf(r21, 1e-30f));
            ax1 = fmaf(K1, sxa[k], ax1);
            ay1 = fmaf(K1, sya[k], ay1);
            az1 = fmaf(K1, sza[k], az1);
        }
    }

    float* op0 = out + ((size_t)b * N_PTS + n0) * 3;
    float* op1 = out + ((size_t)b * N_PTS + n1) * 3;
    op0[0] = ax0; op0[1] = ay0; op0[2] = az0;
    op1[0] = ax1; op1[1] = ay1; op1[2] = az1;
}

extern "C" void kernel_launch(void* const* d_in, const int* in_sizes, int n_in,
                              void* d_out, int out_size, void* d_ws, size_t ws_size,
                              hipStream_t stream) {
    const float* sparse_disp    = (const float*)d_in[0];
    const float* original_cp    = (const float*)d_in[1];
    const float* original_dense = (const float*)d_in[2];
    float* out = (float*)d_out;

    dim3 grid(256);
    dim3 block(256);
    rbf_tps_kernel<<<grid, block, 0, stream>>>(sparse_disp, original_cp,
                                               original_dense, out);
}